// Round 4
// baseline (16.368 us; speedup 1.0000x reference)
//
#include <hip/hip_runtime.h>
#include <math.h>

#define NQ 14
#define TPB 256            // 4 waves/block, one sample per wave
#define WPB 4
#define PI_F 3.14159265358979323846f

__device__ __forceinline__ float2 cmul(float2 a, float2 b) {      // a*b
    return make_float2(a.x * b.x - a.y * b.y, a.x * b.y + a.y * b.x);
}
__device__ __forceinline__ float2 cmulc(float2 a, float2 b) {     // a*conj(b)
    return make_float2(a.x * b.x + a.y * b.y, a.y * b.x - a.x * b.y);
}
__device__ __forceinline__ float2 cadd(float2 a, float2 b) {
    return make_float2(a.x + b.x, a.y + b.y);
}

// <Z_q> = sum_{b,b'} prod_i u_i[b_i] conj(u_i[b'_i]) W_i[k'_i, k_i], with
// k = Ring1(b) prefix parities; W_i = cos(w2_i) Z + sin(w2_i) Y on S_q, else I;
// S_0 = {1..13}, S_q = {0..q}. Contracted as a 13-step chain over the 4-state
// (P,P') prefix-parity space; wire 0 closes the ring (boundary term).
// Lane layout: lane = 4*q + c, c = (b0, b'0) chain column; 56 active lanes.
__global__ __launch_bounds__(TPB, 1)
void qsim_kernel(const float* __restrict__ x, const float* __restrict__ w,
                 float* __restrict__ out) {
    __shared__ float2 su[WPB][NQ][2];   // per-wave u_i (Enc + RX layer-1 on |0>)
    __shared__ float2 scs[WPB][NQ];     // per-wave (cos w2_i, sin w2_i), FULL angle

    const int lane = threadIdx.x & 63;
    const int wv   = threadIdx.x >> 6;
    const int s    = blockIdx.x * WPB + wv;

    if (lane < NQ) {
        // tanh via v_exp_f32: tanh(v) = 1 - 2/(e^{2v}+1)
        const float v  = x[s * NQ + lane];
        const float th = (1.0f - 2.0f / (expf(2.0f * v) + 1.0f)) * PI_F;
        float sn, c;
        sincosf(0.5f * th, &sn, &c);
        const float2 e0 = make_float2(c * c, -c * sn);   // e^{-i th/2} cos
        const float2 e1 = make_float2(c * sn, sn * sn);  // e^{+i th/2} sin
        float sw, cw;
        sincosf(0.5f * w[lane], &sw, &cw);               // layer-1 RX half-angle
        su[wv][lane][0] = make_float2(cw * e0.x + sw * e1.y, cw * e0.y - sw * e1.x);
        su[wv][lane][1] = make_float2(sw * e0.y + cw * e1.x, -sw * e0.x + cw * e1.y);
        float s2, c2;
        sincosf(w[NQ + lane], &s2, &c2);                 // layer-2: FULL angle
        scs[wv][lane] = make_float2(c2, s2);
    }
    __syncthreads();

    float2 U0[NQ], U1[NQ];
    float CC[NQ], SS[NQ];
    #pragma unroll
    for (int i = 0; i < NQ; ++i) {
        U0[i] = su[wv][i][0];
        U1[i] = su[wv][i][1];
        CC[i] = scs[wv][i].x;
        SS[i] = scs[wv][i].y;
    }

    const int q = lane >> 2;      // observable index (lanes with q>=14 idle)
    const int c = lane & 3;       // chain column = (b0, b'0)
    const int b0 = c >> 1, bp0 = c & 1;

    float2 g0 = make_float2(c == 0 ? 1.0f : 0.0f, 0.0f);
    float2 g1 = make_float2(c == 1 ? 1.0f : 0.0f, 0.0f);
    float2 g2 = make_float2(c == 2 ? 1.0f : 0.0f, 0.0f);
    float2 g3 = make_float2(c == 3 ? 1.0f : 0.0f, 0.0f);

    #pragma unroll
    for (int i = 1; i < NQ; ++i) {
        const float2 u0 = U0[i], u1 = U1[i];
        // H[p][P'] = sum_{p'} conj(u[P'^p']) * g[2p+p']
        const float2 H00 = cadd(cmulc(g0, u0), cmulc(g1, u1));
        const float2 H01 = cadd(cmulc(g0, u1), cmulc(g1, u0));
        const float2 H10 = cadd(cmulc(g2, u0), cmulc(g3, u1));
        const float2 H11 = cadd(cmulc(g2, u1), cmulc(g3, u0));
        // K[P][P'] = sum_p u[P^p] * H[p][P']
        const float2 K00 = cadd(cmul(u0, H00), cmul(u1, H10));
        const float2 K01 = cadd(cmul(u0, H01), cmul(u1, H11));
        const float2 K10 = cadd(cmul(u1, H00), cmul(u0, H10));
        const float2 K11 = cadd(cmul(u1, H01), cmul(u0, H11));
        // g[2P+P'] = X[P'][P] * K[P][P'],  X = V_i if (q==0 || i<=q) else I
        // V = [[c, -i s], [i s, -c]]
        const bool useV = (q == 0) || (i <= q);
        const float a  = useV ? CC[i] : 1.0f;
        const float d  = useV ? -CC[i] : 1.0f;
        const float sv = useV ? SS[i] : 0.0f;
        g0 = make_float2(a * K00.x, a * K00.y);            // X[0][0] = c
        g1 = make_float2(-sv * K01.y, sv * K01.x);         // X[1][0] = +i s
        g2 = make_float2(sv * K10.y, -sv * K10.x);         // X[0][1] = -i s
        g3 = make_float2(d * K11.x, d * K11.y);            // X[1][1] = -c
    }

    // boundary (wire 0): W0 = V_0 for q>=1, I for q==0.
    const bool Vb = (q != 0);
    const float a0  = Vb ? CC[0] : 1.0f;
    const float d0  = Vb ? -CC[0] : 1.0f;
    const float sv0 = Vb ? SS[0] : 0.0f;
    const int e = b0 ^ bp0;

    float2 val = make_float2(0.0f, 0.0f);
    #pragma unroll
    for (int P = 0; P < 2; ++P) {
        #pragma unroll
        for (int Pp = 0; Pp < 2; ++Pp) {
            const float2 gv = (P == 0) ? (Pp == 0 ? g0 : g1)
                                       : (Pp == 0 ? g2 : g3);
            const int r = Pp ^ bp0;
            const bool diag = ((P ^ Pp) == e);
            const float m = r ? d0 : a0;
            const float k = r ? sv0 : -sv0;
            val.x += diag ? m * gv.x : -k * gv.y;
            val.y += diag ? m * gv.y : k * gv.x;
        }
    }
    const float2 w0a = b0 ? U1[0] : U0[0];
    const float2 w0b = bp0 ? U1[0] : U0[0];
    const float2 coeff = cmulc(w0a, w0b);          // u_0[b0] * conj(u_0[b'0])
    float res = coeff.x * val.x - coeff.y * val.y; // Re(coeff * val)

    res += __shfl_xor(res, 1);
    res += __shfl_xor(res, 2);

    if (c == 0 && q < NQ) out[s * NQ + q] = res;
}

extern "C" void kernel_launch(void* const* d_in, const int* in_sizes, int n_in,
                              void* d_out, int out_size, void* d_ws, size_t ws_size,
                              hipStream_t stream) {
    const float* x = (const float*)d_in[0];   // [B, 14] float32
    const float* w = (const float*)d_in[1];   // [2, 14] float32
    float* out = (float*)d_out;               // [B, 14] float32
    const int batch = in_sizes[0] / NQ;       // 256
    qsim_kernel<<<batch / WPB, TPB, 0, stream>>>(x, w, out);
}

// Round 5
// 10.927 us; speedup vs baseline: 1.4980x; 1.4980x over previous
//
#include <hip/hip_runtime.h>
#include <math.h>

#define NQ 14
#define TPB 64
#define PI_F 3.14159265358979323846f

__device__ __forceinline__ float2 cmul(float2 a, float2 b) {      // a*b
    return make_float2(a.x * b.x - a.y * b.y, a.x * b.y + a.y * b.x);
}
__device__ __forceinline__ float2 cmulc(float2 a, float2 b) {     // a*conj(b)
    return make_float2(a.x * b.x + a.y * b.y, a.y * b.x - a.x * b.y);
}
__device__ __forceinline__ float2 cadd(float2 a, float2 b) {
    return make_float2(a.x + b.x, a.y + b.y);
}

// Per sample: <Z_q> = sum_{b,b'} prod_i u_i[b_i] conj(u_i[b'_i]) W_i[k'_i, k_i],
// k = Ring1(b): k_j = b_0^..^b_j (j>=1), k_0 = b_1^..^b_13.
// W_i = cos(w2_i) Z + sin(w2_i) Y for i in S_q else I; S_0 = {1..13},
// S_q = {0..q} (q>=1). Contracted as a 13-step chain over the 4-state (P,P')
// prefix-parity space; wire 0 closes the ring (boundary term).
// Lane layout: lane = 4*q + c, c = (b0, b'0) chain column; 56 active lanes.
// One sample per single-wave block: 256 blocks — measured-best dispatch shape
// (round 3: 9.63 us; 4-wave blocks regressed to 16.4 us in round 4).
__global__ __launch_bounds__(TPB, 1)
void qsim_kernel(const float* __restrict__ x, const float* __restrict__ w,
                 float* __restrict__ out) {
    __shared__ float2 su[NQ][2];   // u_i (Enc+RX-layer1 applied to |0>)
    __shared__ float2 scs[NQ];     // (cos w2_i, sin w2_i)  FULL angle

    const int lane = threadIdx.x;
    const int s = blockIdx.x;

    if (lane < NQ) {
        const float th = tanhf(x[s * NQ + lane]) * PI_F;
        float sn, c;
        sincosf(0.5f * th, &sn, &c);
        const float2 e0 = make_float2(c * c, -c * sn);   // e^{-i th/2} cos
        const float2 e1 = make_float2(c * sn, sn * sn);  // e^{+i th/2} sin
        float sw, cw;
        sincosf(0.5f * w[lane], &sw, &cw);               // layer-1 RX half-angle
        su[lane][0] = make_float2(cw * e0.x + sw * e1.y, cw * e0.y - sw * e1.x);
        su[lane][1] = make_float2(sw * e0.y + cw * e1.x, -sw * e0.x + cw * e1.y);
        float s2, c2;
        sincosf(w[NQ + lane], &s2, &c2);                 // layer-2: FULL angle
        scs[lane] = make_float2(c2, s2);
    }
    __syncthreads();

    float2 U0[NQ], U1[NQ];
    float CC[NQ], SS[NQ];
    #pragma unroll
    for (int i = 0; i < NQ; ++i) {
        U0[i] = su[i][0];
        U1[i] = su[i][1];
        CC[i] = scs[i].x;
        SS[i] = scs[i].y;
    }

    const int q = lane >> 2;      // observable index (lanes with q>=14 idle)
    const int c = lane & 3;       // chain column = (b0, b'0)
    const int b0 = c >> 1, bp0 = c & 1;

    float2 g0 = make_float2(c == 0 ? 1.0f : 0.0f, 0.0f);
    float2 g1 = make_float2(c == 1 ? 1.0f : 0.0f, 0.0f);
    float2 g2 = make_float2(c == 2 ? 1.0f : 0.0f, 0.0f);
    float2 g3 = make_float2(c == 3 ? 1.0f : 0.0f, 0.0f);

    #pragma unroll
    for (int i = 1; i < NQ; ++i) {
        const float2 u0 = U0[i], u1 = U1[i];
        // H[p][P'] = sum_{p'} conj(u[P'^p']) * g[2p+p']
        const float2 H00 = cadd(cmulc(g0, u0), cmulc(g1, u1));
        const float2 H01 = cadd(cmulc(g0, u1), cmulc(g1, u0));
        const float2 H10 = cadd(cmulc(g2, u0), cmulc(g3, u1));
        const float2 H11 = cadd(cmulc(g2, u1), cmulc(g3, u0));
        // K[P][P'] = sum_p u[P^p] * H[p][P']
        const float2 K00 = cadd(cmul(u0, H00), cmul(u1, H10));
        const float2 K01 = cadd(cmul(u0, H01), cmul(u1, H11));
        const float2 K10 = cadd(cmul(u1, H00), cmul(u0, H10));
        const float2 K11 = cadd(cmul(u1, H01), cmul(u0, H11));
        // g[2P+P'] = X[P'][P] * K[P][P'],  X = V_i if (q==0 || i<=q) else I
        // V = [[c, -i s], [i s, -c]]
        const bool useV = (q == 0) || (i <= q);
        const float a  = useV ? CC[i] : 1.0f;
        const float d  = useV ? -CC[i] : 1.0f;
        const float sv = useV ? SS[i] : 0.0f;
        g0 = make_float2(a * K00.x, a * K00.y);            // X[0][0] = c
        g1 = make_float2(-sv * K01.y, sv * K01.x);         // X[1][0] = +i s
        g2 = make_float2(sv * K10.y, -sv * K10.x);         // X[0][1] = -i s
        g3 = make_float2(d * K11.x, d * K11.y);            // X[1][1] = -c
    }

    // boundary (wire 0): W0 = V_0 for q>=1, I for q==0.
    const bool Vb = (q != 0);
    const float a0  = Vb ? CC[0] : 1.0f;
    const float d0  = Vb ? -CC[0] : 1.0f;
    const float sv0 = Vb ? SS[0] : 0.0f;
    const int e = b0 ^ bp0;

    float2 val = make_float2(0.0f, 0.0f);
    #pragma unroll
    for (int P = 0; P < 2; ++P) {
        #pragma unroll
        for (int Pp = 0; Pp < 2; ++Pp) {
            const float2 gv = (P == 0) ? (Pp == 0 ? g0 : g1)
                                       : (Pp == 0 ? g2 : g3);
            const int r = Pp ^ bp0;
            const bool diag = ((P ^ Pp) == e);
            const float m = r ? d0 : a0;
            const float k = r ? sv0 : -sv0;
            val.x += diag ? m * gv.x : -k * gv.y;
            val.y += diag ? m * gv.y : k * gv.x;
        }
    }
    const float2 w0a = b0 ? U1[0] : U0[0];
    const float2 w0b = bp0 ? U1[0] : U0[0];
    const float2 coeff = cmulc(w0a, w0b);          // u_0[b0] * conj(u_0[b'0])
    float res = coeff.x * val.x - coeff.y * val.y; // Re(coeff * val)

    res += __shfl_xor(res, 1);
    res += __shfl_xor(res, 2);

    if (c == 0 && q < NQ) out[s * NQ + q] = res;
}

extern "C" void kernel_launch(void* const* d_in, const int* in_sizes, int n_in,
                              void* d_out, int out_size, void* d_ws, size_t ws_size,
                              hipStream_t stream) {
    const float* x = (const float*)d_in[0];   // [B, 14] float32
    const float* w = (const float*)d_in[1];   // [2, 14] float32
    float* out = (float*)d_out;               // [B, 14] float32
    const int batch = in_sizes[0] / NQ;       // 256
    qsim_kernel<<<batch, TPB, 0, stream>>>(x, w, out);
}